// Round 1
// 246.991 us; speedup vs baseline: 1.0261x; 1.0261x over previous
//
#include <hip/hip_runtime.h>

// AirFitMultiHeadDNN — R10: head-split half-blocks for 4 blocks/CU (32 waves).
// Evidence R9: kernel 90.5us with HBM 12%, VALU 28%, Occupancy 40% -> latency
// bound at 16 waves/CU (80KB LDS/block). Heads are independent until the
// final sum and f/e split cleanly at head 10, so each block now handles
// 512 items x 10 heads:
//   f fp16 [5][512][3]h2 = 30,720 B  (bank (3*tid+j)%32, 2-way = free)
//   e 4-bit dword+byte   =  2,560 B
//   T stride-13 padded   =  6,760 B  (gcd(13,32)=1 -> conflict-free idx rows)
//   total 40,040 B -> 4 blocks/CU = 2048 thr/CU (hard cap), VGPR<=64 enforced.
// Halves combine via global_atomic_add_f32 (2 addends, order-independent);
// setup pre-fills out[b]=bo every replay. Halves of a chunk are paired on
// the same XCD (partner at bid+8 in groups of 16) for shared-f-line L2 hits.

#define HH   20
#define NEX  13
#define TST  13                  // padded T row stride (floats)
#define HHF  10                  // heads per half-block
#define WS_M 0
#define WS_T 640
#define NT   512                 // threads = items per block

typedef __attribute__((ext_vector_type(2))) _Float16 half2v;

__device__ __forceinline__ float softplus_fast(float x) {
    return fmaxf(x, 0.0f) + __logf(1.0f + __expf(-fabsf(x)));
}

// ---------------- setup: fold weights into M and T, init out=bo ----------------
__global__ void airfit_setup(const float* __restrict__ emb,
                             const float* __restrict__ Wf,
                             const float* __restrict__ bf,
                             const float* __restrict__ W1,
                             const float* __restrict__ b1,
                             const float* __restrict__ bo,
                             float* __restrict__ ws,
                             float* __restrict__ out, int B)
{
    int t = blockIdx.x * 256 + threadIdx.x;
    if (t < HH * 3 * 10) {                       // M[h][c][o]
        int h = t / 30, c = (t / 10) % 3, o = t % 10;
        float a = 0.0f;
        for (int q = 0; q < 5; ++q)
            a += Wf[c * 5 + q] * W1[(h * 8 + 3 + q) * 10 + o];
        ws[WS_M + (h * 3 + c) * 10 + o] = a;
    }
    if (t < HH * NEX * TST) {                    // T[h][idx][o], o-stride 13
        int h = t / (NEX * TST);
        int r = t - h * (NEX * TST);
        int idx = r / TST, o = r - idx * TST;
        float a = 0.0f;
        if (o < 10) {
            a = b1[h * 10 + o];
            for (int i = 0; i < 3; ++i)
                a += emb[idx * 3 + i] * W1[(h * 8 + i) * 10 + o];
            for (int q = 0; q < 5; ++q)
                a += bf[q] * W1[(h * 8 + 3 + q) * 10 + o];
        }
        ws[WS_T + t] = a;
    }
    // out[b] = bo; the two half-blocks atomically add their partials
    int nv4 = B >> 2;
    float bov = bo[0];
    if (t < nv4) {
        float4 v = { bov, bov, bov, bov };
        reinterpret_cast<float4*>(out)[t] = v;
    } else if (t == nv4) {
        for (int i = nv4 * 4; i < B; ++i) out[i] = bov;
    }
}

// ---------------- main: one half (10 heads) of 512 items per block ----------------
__global__ __launch_bounds__(NT, 8) void airfit_kernel(
    const int*   __restrict__ e,   const float* __restrict__ f,
    const float* __restrict__ ws,  const float* __restrict__ W2,
    const float* __restrict__ b2,  const float* __restrict__ Wo,
    float* __restrict__ out, int B)
{
    __shared__ half2v        s_f[5][NT][3];        // 30,720 B
    __shared__ unsigned int  s_e32[NT];            //  2,048 B
    __shared__ unsigned char s_e8[NT];             //    512 B
    __shared__ float         s_T[HHF * NEX * TST]; //  6,760 B  => 40,040 B

    const int tid = threadIdx.x;
    const int bid = blockIdx.x, nB = gridDim.x;
    int chunk, hf;
    if ((nB & 15) == 0) {       // pair halves of a chunk on the same XCD
        chunk = ((bid >> 4) << 3) | (bid & 7);
        hf    = (bid >> 3) & 1;
    } else {
        chunk = bid >> 1;
        hf    = bid & 1;
    }
    const int base = chunk * NT;
    const int nIt  = min(NT, B - base);

    // ---- stage T half (ws is L2-hot after setup) ----
    for (int t = tid; t < HHF * NEX * TST; t += NT)
        s_T[t] = ws[WS_T + hf * (HHF * NEX * TST) + t];

    // ---- stage f half: lane-contiguous float2 stream -> fp16 ----
    {
        const float2* fg = reinterpret_cast<const float2*>(f);
        const int fbase  = base * 30 + hf * 15;
        const int total2 = nIt * 15;
#pragma unroll
        for (int k = 0; k < 15; ++k) {
            int idx = tid + NT * k;
            if (idx < total2) {
                int item = idx / 15, c2 = idx - item * 15;
                float2 v = fg[fbase + item * 30 + c2];
                int g = c2 / 3, j = c2 - 3 * g;
                s_f[g][item][j] = half2v{ (_Float16)v.x, (_Float16)v.y };
            }
        }
    }

    // ---- stage e half: int2 stream -> 4-bit packed (dword + byte / item) ----
    {
        const int2* eg = reinterpret_cast<const int2*>(e);
        const int ebase  = base * 10 + hf * 5;
        const int total2 = nIt * 5;
#pragma unroll
        for (int k = 0; k < 5; ++k) {
            int idx = tid + NT * k;
            if (idx < total2) {
                int item = idx / 5, p = idx - item * 5;
                int2 v = eg[ebase + item * 10 + p];
                unsigned char pk =
                    (unsigned char)((v.x & 0xf) | ((v.y & 0xf) << 4));
                if (p < 4) ((unsigned char*)s_e32)[item * 4 + p] = pk;
                else       s_e8[item] = pk;
            }
        }
    }

    __syncthreads();                             // only barrier

    if (tid >= nIt) return;

    const float* M  = ws + WS_M;
    const int    hb = hf * HHF;                  // global head base (uniform)

    unsigned ed = s_e32[tid];                    // nibbles for local heads 0..7
    unsigned eb = s_e8[tid];                     // nibbles for local heads 8,9

    float acc = 0.0f;
#pragma unroll
    for (int g = 0; g < 5; ++g) {                // local head pairs
        half2v a0 = s_f[g][tid][0];
        half2v a1 = s_f[g][tid][1];
        half2v a2 = s_f[g][tid][2];
        float ff[6] = { (float)a0.x, (float)a0.y, (float)a1.x,
                        (float)a1.y, (float)a2.x, (float)a2.y };

#pragma unroll
        for (int t = 0; t < 2; ++t) {
            const int hl = 2 * g + t;            // compile-time local head
            const int h  = hb + hl;              // uniform -> s_load path
            unsigned idx = (hl < 8) ? ((ed >> (4 * hl)) & 0xfu)
                                    : ((eb >> (4 * (hl - 8))) & 0xfu);
            const float* Trow = s_T + (hl * NEX + idx) * TST;

            float g0 = ff[3 * t + 0], g1 = ff[3 * t + 1], g2 = ff[3 * t + 2];
            float hacc = b2[h];
#pragma unroll
            for (int o = 0; o < 10; ++o) {
                float a = Trow[o];
                a = fmaf(g0, M[(h * 3 + 0) * 10 + o], a);
                a = fmaf(g1, M[(h * 3 + 1) * 10 + o], a);
                a = fmaf(g2, M[(h * 3 + 2) * 10 + o], a);
                a = fmaxf(a, 0.01f * a);         // leaky_relu
                hacc = fmaf(a, W2[h * 10 + o], hacc);
            }
            acc = fmaf(softplus_fast(hacc), Wo[h], acc);
        }
    }

    atomicAdd(out + base + tid, acc);            // 2 addends -> order-independent
}

extern "C" void kernel_launch(void* const* d_in, const int* in_sizes, int n_in,
                              void* d_out, int out_size, void* d_ws, size_t ws_size,
                              hipStream_t stream) {
    const int*   e   = (const int*)  d_in[0];
    const float* f   = (const float*)d_in[1];
    const float* emb = (const float*)d_in[2];
    const float* Wf  = (const float*)d_in[3];
    const float* bf  = (const float*)d_in[4];
    const float* W1  = (const float*)d_in[5];
    const float* b1  = (const float*)d_in[6];
    const float* W2  = (const float*)d_in[7];
    const float* b2  = (const float*)d_in[8];
    const float* Wo  = (const float*)d_in[9];
    const float* bo  = (const float*)d_in[10];
    float* out = (float*)d_out;
    float* ws  = (float*)d_ws;

    int B = in_sizes[0] / HH;                    // e is (B, 20)

    int sblocks = ((B >> 2) + 1 + 255) / 256;    // covers out-init
    int minb    = (HH * NEX * TST + 255) / 256;  // covers T fold
    if (sblocks < minb) sblocks = minb;
    airfit_setup<<<sblocks, 256, 0, stream>>>(emb, Wf, bf, W1, b1, bo, ws, out, B);

    int nChunks = (B + NT - 1) / NT;
    airfit_kernel<<<2 * nChunks, NT, 0, stream>>>(e, f, ws, W2, b2, Wo, out, B);
}

// Round 3
// 242.211 us; speedup vs baseline: 1.0464x; 1.0197x over previous
//
#include <hip/hip_runtime.h>
#include <hip/hip_fp16.h>

// AirFitMultiHeadDNN — R12: R11 (packed-fp16 inner loop + fdot2 f32 accum)
// rebuilt on clang-native _Float16 x2 vectors; ROCm 7.2 headers lack
// __hmax2 so we use __builtin_elementwise_max -> v_pk_max_f16 and native
// operators -> v_pk_fma_f16.
// Evidence R10: occupancy 40->77% bought only 90.5->85us; VALU 39% is the
// largest pipe, HBM 13%. Wall = total instruction stream (f32 scalar math
// + ~100 scalar ds_read_b32/item-half from TST=13 padding).
// R12 pairs the o-dimension (10 -> 5 x half2):
//   h1 pair: 3x v_pk_fma_f16 + pk leaky;  hacc: v_dot2_f32_f16 (f32 accum
//   -> 10-term sum exact in f32; h1 fp16 err ~1e-3 << 3.9e-2 threshold).
//   T fp16, row stride 6 half2 (24B): 6*idx mod 32 distinct for idx 0..12
//   -> conflict-free; 8B-aligned rows merge to b64+b64+b32 (3 DS/head).
//   M/W2 fp16 in ws on the uniform s_load path (scalar pipe).
// LDS: f 30720 + e 2560 + T 3120 = 36,400B -> 4 blocks/CU = 32 waves (cap).
// Predicted: main dur 85 -> ~60us; VALU instrs ~-40%; conflicts <0.6M.

#define HH   20
#define NEX  13
#define HHF  10                  // heads per half-block
#define NT   512                 // threads = items per block

// ws layout in half2 (4B) slots
#define WS2_M   0                // M2[h][c][p]   : 20*3*5  = 300
#define WS2_W2  320              // W2h[h][p]     : 20*5    = 100
#define WS2_T   448              // T16[h][idx][p]: 20*13*6 = 1560 (p=5 pad)

typedef _Float16 hv2 __attribute__((ext_vector_type(2)));

__device__ __forceinline__ float softplus_fast(float x) {
    return fmaxf(x, 0.0f) + __logf(1.0f + __expf(-fabsf(x)));
}

__device__ __forceinline__ float fdot2f(hv2 a, hv2 b, float c) {
#if __has_builtin(__builtin_amdgcn_fdot2)
    return __builtin_amdgcn_fdot2(a, b, c, false);
#else
    return fmaf((float)a.x, (float)b.x, fmaf((float)a.y, (float)b.y, c));
#endif
}

// ---------------- setup: fold weights into fp16 M2/W2h/T16, init out=bo ----------------
__global__ void airfit_setup(const float* __restrict__ emb,
                             const float* __restrict__ Wf,
                             const float* __restrict__ bf,
                             const float* __restrict__ W1,
                             const float* __restrict__ b1,
                             const float* __restrict__ W2,
                             const float* __restrict__ bo,
                             float* __restrict__ ws,
                             float* __restrict__ out, int B)
{
    int t = blockIdx.x * 256 + threadIdx.x;
    hv2* wsh = reinterpret_cast<hv2*>(ws);

    if (t < 300) {                               // M2[h][c][p] = folded Wf*W1
        int h = t / 15, r = t % 15, c = r / 5, p = r % 5;
        float v[2];
        for (int s = 0; s < 2; ++s) {
            int o = 2 * p + s;
            float a = 0.0f;
            for (int q = 0; q < 5; ++q)
                a += Wf[c * 5 + q] * W1[(h * 8 + 3 + q) * 10 + o];
            v[s] = a;
        }
        wsh[WS2_M + t] = hv2{ (_Float16)v[0], (_Float16)v[1] };
    }
    if (t < 100) {                               // W2h[h][p]
        int h = t / 5, p = t % 5;
        wsh[WS2_W2 + t] = hv2{ (_Float16)W2[h * 10 + 2 * p],
                               (_Float16)W2[h * 10 + 2 * p + 1] };
    }
    if (t < HH * NEX * 6) {                      // T16[h][idx][p], p=5 pad
        int h = t / (NEX * 6), r = t % (NEX * 6), idx = r / 6, p = r % 6;
        float v[2] = { 0.0f, 0.0f };
        if (p < 5) {
            for (int s = 0; s < 2; ++s) {
                int o = 2 * p + s;
                float a = b1[h * 10 + o];
                for (int i = 0; i < 3; ++i)
                    a += emb[idx * 3 + i] * W1[(h * 8 + i) * 10 + o];
                for (int q = 0; q < 5; ++q)
                    a += bf[q] * W1[(h * 8 + 3 + q) * 10 + o];
                v[s] = a;
            }
        }
        wsh[WS2_T + t] = hv2{ (_Float16)v[0], (_Float16)v[1] };
    }
    // out[b] = bo; the two half-blocks atomically add their partials
    int nv4 = B >> 2;
    float bov = bo[0];
    if (t < nv4) {
        float4 v = { bov, bov, bov, bov };
        reinterpret_cast<float4*>(out)[t] = v;
    } else if (t == nv4) {
        for (int i = nv4 * 4; i < B; ++i) out[i] = bov;
    }
}

// ---------------- main: one half (10 heads) of 512 items per block ----------------
__global__ __launch_bounds__(NT, 8) void airfit_kernel(
    const int*   __restrict__ e,   const float* __restrict__ f,
    const float* __restrict__ ws,  const float* __restrict__ b2,
    const float* __restrict__ Wo,  float* __restrict__ out, int B)
{
    __shared__ hv2            s_f[5][NT][3];       // 30,720 B
    __shared__ unsigned int   s_e32[NT];           //  2,048 B
    __shared__ unsigned char  s_e8[NT];            //    512 B
    __shared__ __align__(16) hv2 s_T[HHF * NEX * 6]; // 3,120 B => 36,400 B

    const int tid = threadIdx.x;
    const int bid = blockIdx.x, nB = gridDim.x;
    int chunk, hf;
    if ((nB & 15) == 0) {       // pair halves of a chunk on the same XCD
        chunk = ((bid >> 4) << 3) | (bid & 7);
        hf    = (bid >> 3) & 1;
    } else {
        chunk = bid >> 1;
        hf    = bid & 1;
    }
    const int base = chunk * NT;
    const int nIt  = min(NT, B - base);

    const hv2* wsh = reinterpret_cast<const hv2*>(ws);

    // ---- stage T16 half (ws is L2-hot after setup) ----
    for (int t = tid; t < HHF * NEX * 6; t += NT)
        s_T[t] = wsh[WS2_T + hf * (HHF * NEX * 6) + t];

    // ---- stage f half: lane-contiguous float2 stream -> fp16 pairs ----
    {
        const float2* fg = reinterpret_cast<const float2*>(f);
        const int fbase  = base * 30 + hf * 15;
        const int total2 = nIt * 15;
#pragma unroll
        for (int k = 0; k < 15; ++k) {
            int idx = tid + NT * k;
            if (idx < total2) {
                int item = idx / 15, c2 = idx - item * 15;
                float2 v = fg[fbase + item * 30 + c2];
                int g = c2 / 3, j = c2 - 3 * g;
                s_f[g][item][j] = hv2{ (_Float16)v.x, (_Float16)v.y };
            }
        }
    }

    // ---- stage e half: int2 stream -> 4-bit packed (dword + byte / item) ----
    {
        const int2* eg = reinterpret_cast<const int2*>(e);
        const int ebase  = base * 10 + hf * 5;
        const int total2 = nIt * 5;
#pragma unroll
        for (int k = 0; k < 5; ++k) {
            int idx = tid + NT * k;
            if (idx < total2) {
                int item = idx / 5, p = idx - item * 5;
                int2 v = eg[ebase + item * 10 + p];
                unsigned char pk =
                    (unsigned char)((v.x & 0xf) | ((v.y & 0xf) << 4));
                if (p < 4) ((unsigned char*)s_e32)[item * 4 + p] = pk;
                else       s_e8[item] = pk;
            }
        }
    }

    __syncthreads();                             // only barrier

    if (tid >= nIt) return;

    const int hb = hf * HHF;                     // global head base (uniform)
    const hv2 lk2 = hv2{ (_Float16)0.01f, (_Float16)0.01f };

    unsigned ed = s_e32[tid];                    // nibbles for local heads 0..7
    unsigned eb = s_e8[tid];                     // nibbles for local heads 8,9

    float acc = 0.0f;
#pragma unroll
    for (int g = 0; g < 5; ++g) {                // local head pairs
        hv2 a0 = s_f[g][tid][0];
        hv2 a1 = s_f[g][tid][1];
        hv2 a2 = s_f[g][tid][2];
        _Float16 bb[6] = { a0.x, a0.y, a1.x, a1.y, a2.x, a2.y };

#pragma unroll
        for (int t = 0; t < 2; ++t) {
            const int hl = 2 * g + t;            // compile-time local head
            const int h  = hb + hl;              // uniform -> s_load path
            unsigned idx = (hl < 8) ? ((ed >> (4 * hl)) & 0xfu)
                                    : ((eb >> (4 * (hl - 8))) & 0xfu);
            const hv2* Tr = s_T + (hl * NEX + (int)idx) * 6;
            hv2 tp[5] = { Tr[0], Tr[1], Tr[2], Tr[3], Tr[4] };

            hv2 g0 = hv2{ bb[3 * t + 0], bb[3 * t + 0] };
            hv2 g1 = hv2{ bb[3 * t + 1], bb[3 * t + 1] };
            hv2 g2 = hv2{ bb[3 * t + 2], bb[3 * t + 2] };
            const hv2* Mh  = wsh + WS2_M + h * 15;   // [c][p], uniform
            const hv2* W2h = wsh + WS2_W2 + h * 5;   // uniform

            float hacc = b2[h];
#pragma unroll
            for (int p = 0; p < 5; ++p) {
                hv2 v = g0 * Mh[p] + tp[p];          // v_pk_fma_f16
                v = g1 * Mh[5 + p] + v;
                v = g2 * Mh[10 + p] + v;
                v = __builtin_elementwise_max(v, v * lk2);  // v_pk_max_f16
                hacc = fdot2f(v, W2h[p], hacc);      // f32 accumulate
            }
            acc = fmaf(softplus_fast(hacc), Wo[h], acc);
        }
    }

    atomicAdd(out + base + tid, acc);            // 2 addends -> order-independent
}

extern "C" void kernel_launch(void* const* d_in, const int* in_sizes, int n_in,
                              void* d_out, int out_size, void* d_ws, size_t ws_size,
                              hipStream_t stream) {
    const int*   e   = (const int*)  d_in[0];
    const float* f   = (const float*)d_in[1];
    const float* emb = (const float*)d_in[2];
    const float* Wf  = (const float*)d_in[3];
    const float* bf  = (const float*)d_in[4];
    const float* W1  = (const float*)d_in[5];
    const float* b1  = (const float*)d_in[6];
    const float* W2  = (const float*)d_in[7];
    const float* b2  = (const float*)d_in[8];
    const float* Wo  = (const float*)d_in[9];
    const float* bo  = (const float*)d_in[10];
    float* out = (float*)d_out;
    float* ws  = (float*)d_ws;

    int B = in_sizes[0] / HH;                    // e is (B, 20)

    int sblocks = ((B >> 2) + 1 + 255) / 256;    // covers out-init
    int minb    = (HH * NEX * 6 + 255) / 256;    // covers T16 fold
    if (sblocks < minb) sblocks = minb;
    airfit_setup<<<sblocks, 256, 0, stream>>>(emb, Wf, bf, W1, b1, W2, bo,
                                              ws, out, B);

    int nChunks = (B + NT - 1) / NT;
    airfit_kernel<<<2 * nChunks, NT, 0, stream>>>(e, f, ws, b2, Wo, out, B);
}